// Round 1
// baseline (296.752 us; speedup 1.0000x reference)
//
#include <hip/hip_runtime.h>
#include <math.h>

// Problem constants
#define B_   64
#define L_   577
#define D_   512
#define E_   1024
#define H_   512
#define K_   288            // selected tokens per batch
#define N_   (B_ * K_)      // 18432 total rows
#define KBIG 1024           // concatenated K for fused GEMM2
#define MTILES (N_ / 128)   // 144

typedef __attribute__((ext_vector_type(8))) __bf16 bf16x8;
typedef __attribute__((ext_vector_type(4))) float f32x4;
typedef __attribute__((ext_vector_type(4))) unsigned short ushort4v;
typedef __attribute__((ext_vector_type(8))) unsigned short ushort8v;

// ---------------- workspace layout (bytes) ----------------
#define OFF_WBIG    0                    // 1024*1024 bf16 = 2,097,152
#define OFF_W0B     2097152              // 512*512 bf16   =   524,288
#define OFF_BIASBIG 2621440              // 1024 f32
#define OFF_SCSH    2625536              // 1024 f32 (sc=rsig*gamma, sh=beta-mu*sc)
#define OFF_IDX     2629632              // 18432 i32 = 73,728
#define OFF_PSUM    2703360              // 144*512 f32 = 294,912
#define OFF_PSQ     2998272              // 144*512 f32 = 294,912
#define OFF_ABIG    3555328              // N*1024 bf16 = 37,748,736

static __device__ __forceinline__ unsigned short f2bf(float f) {
  unsigned int u = __builtin_bit_cast(unsigned int, f);
  u = (u + 0x7fffu + ((u >> 16) & 1u)) >> 16;
  return (unsigned short)u;
}
static __device__ __forceinline__ float bf2f(unsigned short s) {
  unsigned int u = ((unsigned int)s) << 16;
  return __builtin_bit_cast(float, u);
}

// float atomic max via CAS (order-independent, exact)
static __device__ __forceinline__ void atomicMaxF(float* addr, float val) {
  unsigned int* ua = (unsigned int*)addr;
  unsigned int vu = __builtin_bit_cast(unsigned int, val);
  unsigned int cur = __builtin_bit_cast(unsigned int, -INFINITY);
  while (true) {
    unsigned int prev = atomicCAS(ua, cur, vu);
    if (prev == cur) break;                                   // stored
    if (__builtin_bit_cast(float, prev) >= val) break;        // existing >= val
    cur = prev;
  }
}

#define GLOAD_LDS16(g, l)                                          \
  __builtin_amdgcn_global_load_lds(                                \
      (const __attribute__((address_space(1))) void*)(g),          \
      (__attribute__((address_space(3))) void*)(l), 16, 0, 0)

// ---------------- kernel 1: pack Wbig(bf16)=[fc_w|mlp_w1], biasbig=fc_b+b1,
//                  W0(bf16), init d_out=-inf, AND top-k (fused, block range)
__global__ __launch_bounds__(256) void prep_topk_kernel(
    const float* __restrict__ fc_w, const float* __restrict__ fc_b,
    const float* __restrict__ w0,   const float* __restrict__ w1,
    const float* __restrict__ b1,   const float* __restrict__ atten,
    unsigned short* __restrict__ wbig, unsigned short* __restrict__ w0b,
    float* __restrict__ biasbig, float* __restrict__ out,
    int* __restrict__ idx) {
  __shared__ float s[L_];
  if (blockIdx.x < 1280) {
    // ---- prep part (identical to previous prep_kernel, outenc -> out=-inf)
    int gid = blockIdx.x * 256 + threadIdx.x;    // 327680 total
    if (gid < 65536) out[gid] = -INFINITY;       // identity for max
    if (gid < 262144) {                          // wbig: 1024 rows x 256 f4-cols
      int e  = gid >> 8;
      int c4 = gid & 255;
      float4 v;
      if (c4 < 128) v = ((const float4*)(fc_w + e * D_))[c4];
      else          v = ((const float4*)(w1   + e * H_))[c4 - 128];
      ushort4v o = { f2bf(v.x), f2bf(v.y), f2bf(v.z), f2bf(v.w) };
      ((ushort4v*)wbig)[gid] = o;
      if (gid < E_) biasbig[gid] = fc_b[gid] + b1[gid];
    } else {                                     // w0b: 512x512
      int i2 = gid - 262144;                     // 65536
      float4 v = ((const float4*)w0)[i2];
      ushort4v o = { f2bf(v.x), f2bf(v.y), f2bf(v.z), f2bf(v.w) };
      ((ushort4v*)w0b)[i2] = o;
    }
  } else {
    // ---- stable top-k per batch via rank
    int b = blockIdx.x - 1280;                   // 0..63
    const float* row = atten + (size_t)b * L_ * L_;   // atten[b][0][:]
    for (int i = threadIdx.x; i < L_; i += 256) s[i] = (i == 0) ? -1.0f : row[i];
    __syncthreads();
    for (int i = threadIdx.x; i < L_; i += 256) {
      float si = s[i];
      int rank = 0;
      for (int j = 0; j < L_; ++j) {
        float sj = s[j];
        rank += (sj > si) || (sj == si && j < i);
      }
      if (rank < K_) idx[b * K_ + rank] = i;
    }
  }
}

// ---------------- kernel 2: gather + L2 normalize -> Abig[:,0:512] (bf16)
__global__ __launch_bounds__(128) void gather_norm_kernel(
    const float* __restrict__ base, const int* __restrict__ idx,
    unsigned short* __restrict__ abig) {
  int r = blockIdx.x;            // 0..N_-1
  int b = r / K_;
  int tok = idx[r];
  const float* src = base + ((size_t)b * L_ + tok) * D_;
  float4 v = ((const float4*)src)[threadIdx.x];     // 128 thr * 4 = 512
  float ss = v.x * v.x + v.y * v.y + v.z * v.z + v.w * v.w;
  #pragma unroll
  for (int o = 32; o > 0; o >>= 1) ss += __shfl_down(ss, o, 64);
  __shared__ float wsum[2];
  if ((threadIdx.x & 63) == 0) wsum[threadIdx.x >> 6] = ss;
  __syncthreads();
  float total = wsum[0] + wsum[1];
  float inv = 1.0f / (sqrtf(total) + 1e-8f);
  ushort4v o4 = { f2bf(v.x * inv), f2bf(v.y * inv), f2bf(v.z * inv), f2bf(v.w * inv) };
  ((ushort4v*)(abig + (size_t)r * KBIG))[threadIdx.x] = o4;
}

// ---------------- bf16 MFMA GEMM, 128x128 tile, BK=64, 4 waves.
// LDS tile: 128 rows x 64 cols bf16, 8 slots of 8 cols per row (128B rows).
// XOR swizzle: slot s of row r holds global col-block s ^ (r&7).
// Staging (4 issues q per matrix): linear idx = q*256 + wave*64 + lane;
// row = q*32 + wave*8 + (lane>>3); LDS dst = base + 16*lane (m104 rule);
// lane fetches global col-block (lane&7) ^ ((lane>>3)&7) [== slot ^ (row&7)].
// Reader: frag for global k-block (4kk+quad) at slot (4kk+quad)^(l15&7);
// each lane-octet covers 8 distinct bank groups -> conflict-free.
// MODE 0 (GEMM1): write pre-BN h as bf16 + per-mtile BN partial sum/sumsq.
// MODE 1 (GEMM2): A-half k>=512 is PRE-BN h: reg-stage with fused
//   BN affine + ReLU (bit-identical layout + rounding to old bn_apply pass);
//   no C write; fused per-batch column max via atomicMaxF directly to d_out.
template <int MODE>
__global__ __launch_bounds__(256) void gemm_mfma_kernel(
    const unsigned short* __restrict__ A, int lda,
    const unsigned short* __restrict__ W, int ldw,
    const float* __restrict__ bias,
    unsigned short* __restrict__ Cbf, int ldc, int K,
    float* __restrict__ psum, float* __restrict__ psq,
    const float* __restrict__ scsh, float* __restrict__ outf) {
  __shared__ unsigned short As[128 * 64];
  __shared__ unsigned short Bs[128 * 64];
  __shared__ float s_sum[4][64];
  __shared__ float s_sq[4][64];
  const int tid  = threadIdx.x;
  const int wave = tid >> 6;
  const int lane = tid & 63;
  const int m0 = blockIdx.x * 128;
  const int n0 = blockIdx.y * 128;

  const int srow = wave * 8 + (lane >> 3);                 // + q*32
  const int g8   = ((lane & 7) ^ ((lane >> 3) & 7)) * 8;   // swizzled global col
  const int ldst = (wave * 64 + lane) * 8;                 // + q*2048 (ushorts)

  const int quad = lane >> 4;
  const int l15  = lane & 15;
  const int wm = (wave & 1) * 64;
  const int wn = (wave >> 1) * 64;
  const int slot0 = quad ^ (l15 & 7);          // kk adds XOR 4

  f32x4 acc[4][4];
  #pragma unroll
  for (int i = 0; i < 4; ++i)
    #pragma unroll
    for (int j = 0; j < 4; ++j)
      acc[i][j] = (f32x4)(0.0f);

  for (int k0 = 0; k0 < K; k0 += 64) {
    if (MODE == 0 || k0 < H_) {
      #pragma unroll
      for (int q = 0; q < 4; ++q) {
        GLOAD_LDS16(A + (size_t)(m0 + q * 32 + srow) * lda + k0 + g8,
                    &As[q * 2048 + ldst]);
        GLOAD_LDS16(W + (size_t)(n0 + q * 32 + srow) * ldw + k0 + g8,
                    &Bs[q * 2048 + ldst]);
      }
    } else {
      // B half: still direct global->LDS (issued first, stays async)
      #pragma unroll
      for (int q = 0; q < 4; ++q)
        GLOAD_LDS16(W + (size_t)(n0 + q * 32 + srow) * ldw + k0 + g8,
                    &Bs[q * 2048 + ldst]);
      // A half is pre-BN h: reg-stage + fused BN affine + ReLU.
      // Same global src addr, same LDS dst addr as the GLOAD path -> layout
      // (incl. XOR swizzle) is unchanged; f2bf at the same rounding point
      // the old bn_apply pass used -> bit-identical MFMA inputs.
      const int c0 = k0 - H_ + g8;                 // 0..504, multiple of 8
      float4 sa = *(const float4*)&scsh[c0];
      float4 sb = *(const float4*)&scsh[c0 + 4];
      float4 ha = *(const float4*)&scsh[512 + c0];
      float4 hb = *(const float4*)&scsh[512 + c0 + 4];
      float sc[8] = {sa.x, sa.y, sa.z, sa.w, sb.x, sb.y, sb.z, sb.w};
      float sh[8] = {ha.x, ha.y, ha.z, ha.w, hb.x, hb.y, hb.z, hb.w};
      #pragma unroll
      for (int q = 0; q < 4; ++q) {
        ushort8v v = *(const ushort8v*)(A + (size_t)(m0 + q * 32 + srow) * lda
                                        + k0 + g8);
        ushort8v o;
        #pragma unroll
        for (int j = 0; j < 8; ++j)
          o[j] = f2bf(fmaxf(bf2f(v[j]) * sc[j] + sh[j], 0.0f));
        *(ushort8v*)&As[q * 2048 + ldst] = o;
      }
    }
    __syncthreads();
    #pragma unroll
    for (int kk = 0; kk < 2; ++kk) {
      const int slot = slot0 ^ (kk * 4);
      bf16x8 af[4], bfr[4];
      #pragma unroll
      for (int i = 0; i < 4; ++i)
        af[i] = *(const bf16x8*)&As[(wm + 16 * i + l15) * 64 + slot * 8];
      #pragma unroll
      for (int j = 0; j < 4; ++j)
        bfr[j] = *(const bf16x8*)&Bs[(wn + 16 * j + l15) * 64 + slot * 8];
      #pragma unroll
      for (int i = 0; i < 4; ++i)
        #pragma unroll
        for (int j = 0; j < 4; ++j)
          acc[i][j] = __builtin_amdgcn_mfma_f32_16x16x32_bf16(af[i], bfr[j], acc[i][j], 0, 0, 0);
    }
    __syncthreads();
  }

  // epilogue: C/D layout col=lane&15, row=quad*4+reg
  if (MODE == 0) {
    // write pre-BN h (bf16) + per-column partial sum/sumsq over 128 rows
    #pragma unroll
    for (int j = 0; j < 4; ++j) {
      int col = n0 + wn + 16 * j + l15;
      float bb = bias[col];
      float sm = 0.f, sq = 0.f;
      #pragma unroll
      for (int i = 0; i < 4; ++i) {
        int row_base = m0 + wm + 16 * i + quad * 4;
        #pragma unroll
        for (int r = 0; r < 4; ++r) {
          float v = acc[i][j][r] + bb;
          Cbf[(size_t)(row_base + r) * ldc + col] = f2bf(v);
          sm += v; sq += v * v;
        }
      }
      sm += __shfl_xor(sm, 16, 64); sm += __shfl_xor(sm, 32, 64);
      sq += __shfl_xor(sq, 16, 64); sq += __shfl_xor(sq, 32, 64);
      if (quad == 0) { s_sum[wave][j * 16 + l15] = sm; s_sq[wave][j * 16 + l15] = sq; }
    }
    __syncthreads();
    if (tid < 128) {
      int half = tid >> 6;          // 0: waves 0,1 (cols 0..63); 1: waves 2,3
      int c = tid & 63;
      float sm = s_sum[half * 2][c] + s_sum[half * 2 + 1][c];
      float sq = s_sq[half * 2][c] + s_sq[half * 2 + 1][c];
      int col = n0 + half * 64 + c;
      psum[blockIdx.x * H_ + col] = sm;
      psq [blockIdx.x * H_ + col] = sq;
    }
  } else {
    // fused max over rows, grouped by batch (16-row bands are batch-uniform)
    #pragma unroll
    for (int j = 0; j < 4; ++j) {
      int col = n0 + wn + 16 * j + l15;
      float bb = bias[col];
      float m[4];
      #pragma unroll
      for (int i = 0; i < 4; ++i) {
        float v = fmaxf(fmaxf(acc[i][j][0], acc[i][j][1]),
                        fmaxf(acc[i][j][2], acc[i][j][3]));
        m[i] = v + bb;
      }
      #pragma unroll
      for (int i = 0; i < 4; ++i) {
        m[i] = fmaxf(m[i], __shfl_xor(m[i], 16, 64));
        m[i] = fmaxf(m[i], __shfl_xor(m[i], 32, 64));
      }
      if (quad == 0) {
        int base = m0 + wm;
        int cb = base / K_;
        float cur = m[0];
        #pragma unroll
        for (int i = 1; i < 4; ++i) {
          int bi = (base + 16 * i) / K_;
          if (bi == cb) cur = fmaxf(cur, m[i]);
          else { atomicMaxF(&outf[cb * E_ + col], cur); cur = m[i]; cb = bi; }
        }
        atomicMaxF(&outf[cb * E_ + col], cur);
      }
    }
  }
}

// ---------------- BN stats reduce -> sc = rsig*gamma, sh = beta - mu*sc
__global__ __launch_bounds__(256) void bn_stats2_kernel(
    const float* __restrict__ psum, const float* __restrict__ psq,
    const float* __restrict__ gamma, const float* __restrict__ beta,
    float* __restrict__ scsh) {
  __shared__ float ls[8][32], lq[8][32];
  int c32 = threadIdx.x & 31;
  int slice = threadIdx.x >> 5;               // 8 slices x 18 mtiles = 144
  int c = blockIdx.x * 32 + c32;              // 16 blocks
  float S = 0.f, Q = 0.f;
  for (int i = 0; i < 18; ++i) {
    int mx = slice * 18 + i;
    S += psum[mx * H_ + c];
    Q += psq [mx * H_ + c];
  }
  ls[slice][c32] = S; lq[slice][c32] = Q;
  __syncthreads();
  if (slice == 0) {
    float St = 0.f, Qt = 0.f;
    #pragma unroll
    for (int s = 0; s < 8; ++s) { St += ls[s][c32]; Qt += lq[s][c32]; }
    const float invN = 1.0f / (float)N_;
    float mu = St * invN;
    float var = Qt * invN - mu * mu;
    float sc = rsqrtf(var + 1e-5f) * gamma[c];
    scsh[c] = sc;
    scsh[512 + c] = beta[c] - mu * sc;
  }
}

extern "C" void kernel_launch(void* const* d_in, const int* in_sizes, int n_in,
                              void* d_out, int out_size, void* d_ws, size_t ws_size,
                              hipStream_t stream) {
  const float* base  = (const float*)d_in[0];   // [64,577,512]
  const float* atten = (const float*)d_in[1];   // [64,577,577]
  const float* fc_w  = (const float*)d_in[2];   // [1024,512]
  const float* fc_b  = (const float*)d_in[3];   // [1024]
  const float* w0    = (const float*)d_in[4];   // [512,512]
  const float* b0    = (const float*)d_in[5];   // [512]
  const float* gamma = (const float*)d_in[6];   // [512]
  const float* beta  = (const float*)d_in[7];   // [512]
  const float* w1    = (const float*)d_in[8];   // [1024,512]
  const float* b1    = (const float*)d_in[9];   // [1024]
  float* out = (float*)d_out;

  char* ws = (char*)d_ws;
  unsigned short* wbig    = (unsigned short*)(ws + OFF_WBIG);
  unsigned short* w0b     = (unsigned short*)(ws + OFF_W0B);
  float*          biasbig = (float*)(ws + OFF_BIASBIG);
  float*          scsh    = (float*)(ws + OFF_SCSH);
  int*            idx     = (int*)  (ws + OFF_IDX);
  float*          psum    = (float*)(ws + OFF_PSUM);
  float*          psq     = (float*)(ws + OFF_PSQ);
  unsigned short* abig    = (unsigned short*)(ws + OFF_ABIG);

  // 1. pack fused weight/bias (bf16) + init d_out=-inf + top-k (fused)
  prep_topk_kernel<<<1344, 256, 0, stream>>>(fc_w, fc_b, w0, w1, b1, atten,
                                             wbig, w0b, biasbig, out, idx);
  // 2. gather + l2norm -> Abig[:,0:512] bf16
  gather_norm_kernel<<<N_, 128, 0, stream>>>(base, idx, abig);
  // 3. GEMM1: pre-BN h (bf16) -> Abig[:,512:1024] + fused BN partial stats
  {
    dim3 grid(MTILES, H_ / 128);
    gemm_mfma_kernel<0><<<grid, 256, 0, stream>>>(abig, KBIG, w0b, D_, b0,
                                                  abig + H_, KBIG, D_,
                                                  psum, psq, nullptr, nullptr);
  }
  // 4. BN stats reduce -> sc/sh
  bn_stats2_kernel<<<16, 256, 0, stream>>>(psum, psq, gamma, beta, scsh);
  // 5. fused GEMM2: BN-apply+ReLU on A-staging (k>=512) + per-batch column
  //    max straight into d_out (no bn_apply pass, no decode pass)
  {
    dim3 grid(MTILES, E_ / 128);
    gemm_mfma_kernel<1><<<grid, 256, 0, stream>>>(abig, KBIG, wbig, KBIG, biasbig,
                                                  nullptr, 0, KBIG, nullptr, nullptr,
                                                  scsh, out);
  }
}